// Round 1
// baseline (247.443 us; speedup 1.0000x reference)
//
#include <hip/hip_runtime.h>

typedef short s8v __attribute__((ext_vector_type(8)));
typedef float f4v __attribute__((ext_vector_type(4)));

#define NB 4
#define LQ 2048
#define LKK 2048
#define XS 1024
#define PDD 128

#define KST 136  // K/Q LDS stride (ushorts): 272B = 16*17, 2-way banks
#define VST 72   // vT LDS stride: 144B = 16*9
#define PST 68   // P LDS stride (floats): 272B

__device__ __forceinline__ ushort f2bf(float x) {
  union { float f; uint u; } v; v.f = x;
  uint r = (v.u + 0x7fffu + ((v.u >> 16) & 1u)) >> 16;
  return (ushort)r;
}

// ---------------- W transpose + bf16 cast: Wt[p][n][k] = W_p[k][n] ----------------
__global__ __launch_bounds__(256) void k_wtrans(const float* __restrict__ Wq,
                                                const float* __restrict__ Wk,
                                                const float* __restrict__ Wv,
                                                ushort* __restrict__ Wt) {
  int p = blockIdx.y;
  const float* W = (p == 0) ? Wq : (p == 1) ? Wk : Wv;
  ushort* out = Wt + (size_t)p * (PDD * XS);
  int t = threadIdx.x;
  int n = t >> 1;
  int kk0 = (t & 1) * 16;
  int k0 = blockIdx.x * 32;
  ushort tmp[16];
#pragma unroll
  for (int i = 0; i < 16; ++i) tmp[i] = f2bf(W[(size_t)(k0 + kk0 + i) * PDD + n]);
  uint4 u0, u1;
  u0.x = tmp[0] | ((uint)tmp[1] << 16);  u0.y = tmp[2] | ((uint)tmp[3] << 16);
  u0.z = tmp[4] | ((uint)tmp[5] << 16);  u0.w = tmp[6] | ((uint)tmp[7] << 16);
  u1.x = tmp[8] | ((uint)tmp[9] << 16);  u1.y = tmp[10] | ((uint)tmp[11] << 16);
  u1.z = tmp[12] | ((uint)tmp[13] << 16); u1.w = tmp[14] | ((uint)tmp[15] << 16);
  uint4* dst = (uint4*)&out[n * XS + k0 + kk0];
  dst[0] = u0; dst[1] = u1;
}

// ---------------- projections: q = (x@Wq+bq)*scale ; k,v = y@W+b (bf16 out) -------
__global__ __launch_bounds__(256) void k_proj(const float* __restrict__ x,
                                              const float* __restrict__ y,
                                              const ushort* __restrict__ Wt,
                                              const float* __restrict__ bq,
                                              const float* __restrict__ bk,
                                              const float* __restrict__ bv,
                                              ushort* __restrict__ qo,
                                              ushort* __restrict__ ko,
                                              ushort* __restrict__ vo) {
  int p = blockIdx.y;  // 0: q from x ; 1: k AND v from y
  const float* in = (p == 0) ? x : y;
  int row0 = blockIdx.x * 64;
  __shared__ ushort As[64 * 56];       // stride 56: 112B = 16*7 aligned, 2-way banks
  __shared__ ushort Bs[2][128 * 56];
  int t = threadIdx.x, wave = t >> 6, lane = t & 63, quad = lane >> 4, lc = lane & 15;
  const f4v z4 = {0.f, 0.f, 0.f, 0.f};
  f4v acc0[8], acc1[8];
#pragma unroll
  for (int i = 0; i < 8; ++i) { acc0[i] = z4; acc1[i] = z4; }
  const ushort* wt0 = Wt + ((p == 0) ? 0 : (PDD * XS));
  const ushort* wt1 = Wt + 2 * (PDD * XS);
  for (int k0 = 0; k0 < XS; k0 += 32) {
    {  // stage A tile [64 x 32] fp32 -> bf16 LDS
      int r = t >> 2, c0 = (t & 3) * 8;
      const float* src = in + (size_t)(row0 + r) * XS + k0 + c0;
      float4 a0 = *(const float4*)src;
      float4 a1 = *(const float4*)(src + 4);
      uint4 pk;
      pk.x = f2bf(a0.x) | ((uint)f2bf(a0.y) << 16);
      pk.y = f2bf(a0.z) | ((uint)f2bf(a0.w) << 16);
      pk.z = f2bf(a1.x) | ((uint)f2bf(a1.y) << 16);
      pk.w = f2bf(a1.z) | ((uint)f2bf(a1.w) << 16);
      *(uint4*)&As[r * 56 + c0] = pk;
    }
    {  // stage B tiles [128 n x 32 k] bf16 from Wt (row-contiguous)
      int n = t >> 1, kk0 = (t & 1) * 16;
      const ushort* s0 = wt0 + n * XS + k0 + kk0;
      uint4 u0 = *(const uint4*)s0;
      uint4 u1 = *(const uint4*)(s0 + 8);
      *(uint4*)&Bs[0][n * 56 + kk0] = u0;
      *(uint4*)&Bs[0][n * 56 + kk0 + 8] = u1;
      if (p == 1) {
        const ushort* s1 = wt1 + n * XS + k0 + kk0;
        uint4 w0 = *(const uint4*)s1;
        uint4 w1 = *(const uint4*)(s1 + 8);
        *(uint4*)&Bs[1][n * 56 + kk0] = w0;
        *(uint4*)&Bs[1][n * 56 + kk0 + 8] = w1;
      }
    }
    __syncthreads();
    s8v a = *(const s8v*)&As[(wave * 16 + lc) * 56 + quad * 8];
#pragma unroll
    for (int nt = 0; nt < 8; ++nt) {
      s8v b0 = *(const s8v*)&Bs[0][(nt * 16 + lc) * 56 + quad * 8];
      acc0[nt] = __builtin_amdgcn_mfma_f32_16x16x32_bf16(a, b0, acc0[nt], 0, 0, 0);
    }
    if (p == 1) {
#pragma unroll
      for (int nt = 0; nt < 8; ++nt) {
        s8v b1 = *(const s8v*)&Bs[1][(nt * 16 + lc) * 56 + quad * 8];
        acc1[nt] = __builtin_amdgcn_mfma_f32_16x16x32_bf16(a, b1, acc1[nt], 0, 0, 0);
      }
    }
    __syncthreads();
  }
  const float qscale = 0.08838834764831845f;  // 1/sqrt(128), folded into q
  const float* bias0 = (p == 0) ? bq : bk;
  ushort* out0 = (p == 0) ? qo : ko;
  float sc0 = (p == 0) ? qscale : 1.0f;
#pragma unroll
  for (int nt = 0; nt < 8; ++nt) {
    int col = nt * 16 + lc;
    float bb = bias0[col];
#pragma unroll
    for (int g = 0; g < 4; ++g) {
      int r = row0 + wave * 16 + quad * 4 + g;  // C-layout: row = quad*4+reg
      out0[(size_t)r * PDD + col] = f2bf((acc0[nt][g] + bb) * sc0);
    }
  }
  if (p == 1) {
#pragma unroll
    for (int nt = 0; nt < 8; ++nt) {
      int col = nt * 16 + lc;
      float bb = bv[col];
#pragma unroll
      for (int g = 0; g < 4; ++g) {
        int r = row0 + wave * 16 + quad * 4 + g;
        vo[(size_t)r * PDD + col] = f2bf(acc1[nt][g] + bb);
      }
    }
  }
}

// ---------------- v -> vT [B][128][LK] (LDS tiled transpose) ----------------------
__global__ __launch_bounds__(256) void k_vtrans(const ushort* __restrict__ v,
                                                ushort* __restrict__ vt) {
  __shared__ ushort L[64 * KST];
  int b = blockIdx.y;
  int j0 = blockIdx.x * 64;
  int t = threadIdx.x;
  { int r = t >> 2, c0 = (t & 3) * 32;
    const uint4* src = (const uint4*)(v + ((size_t)(b * LKK + j0 + r) * PDD + c0));
    uint4* dst = (uint4*)&L[r * KST + c0];
    dst[0] = src[0]; dst[1] = src[1]; dst[2] = src[2]; dst[3] = src[3];
  }
  __syncthreads();
  int d = t >> 1, jj0 = (t & 1) * 32;
  ushort tmp[32];
#pragma unroll
  for (int i = 0; i < 32; ++i) tmp[i] = L[(jj0 + i) * KST + d];
  uint4 uu[4];
#pragma unroll
  for (int w = 0; w < 4; ++w) {
    uu[w].x = tmp[w * 8 + 0] | ((uint)tmp[w * 8 + 1] << 16);
    uu[w].y = tmp[w * 8 + 2] | ((uint)tmp[w * 8 + 3] << 16);
    uu[w].z = tmp[w * 8 + 4] | ((uint)tmp[w * 8 + 5] << 16);
    uu[w].w = tmp[w * 8 + 6] | ((uint)tmp[w * 8 + 7] << 16);
  }
  uint4* dst = (uint4*)(vt + ((size_t)(b * PDD + d) * LKK + j0 + jj0));
  dst[0] = uu[0]; dst[1] = uu[1]; dst[2] = uu[2]; dst[3] = uu[3];
}

// ---------------- fused attention: online softmax (unmasked l), masked PV ---------
__global__ __launch_bounds__(256) void k_attn(const ushort* __restrict__ qg,
                                              const ushort* __restrict__ kg,
                                              const ushort* __restrict__ vtg,
                                              const int* __restrict__ maskp,
                                              float* __restrict__ out) {
  __shared__ ushort Ks[64 * KST];
  __shared__ ushort Vs[PDD * VST];
  __shared__ float Ps[4][16 * PST];
  int b = blockIdx.y;
  int q0 = blockIdx.x * 64;
  int t = threadIdx.x;
  int wave = t >> 6, lane = t & 63, quad = lane >> 4, lc = lane & 15;
  int domask = *maskp;

  {  // stage Q tile into Ks (reused buffer)
    int r = t >> 2, c0 = (t & 3) * 32;
    const uint4* src = (const uint4*)(qg + ((size_t)(b * LQ + q0 + r) * PDD + c0));
    uint4* dst = (uint4*)&Ks[r * KST + c0];
    dst[0] = src[0]; dst[1] = src[1]; dst[2] = src[2]; dst[3] = src[3];
  }
  __syncthreads();
  s8v aq[4];  // Q A-frags: A[m=lc][k=quad*8+j], 4 k-chunks of 32
#pragma unroll
  for (int kc = 0; kc < 4; ++kc)
    aq[kc] = *(const s8v*)&Ks[(wave * 16 + lc) * KST + kc * 32 + quad * 8];

  const f4v z4 = {0.f, 0.f, 0.f, 0.f};
  f4v acc[8];
#pragma unroll
  for (int i = 0; i < 8; ++i) acc[i] = z4;
  float m_i[4] = {-1e30f, -1e30f, -1e30f, -1e30f};
  float l_i[4] = {0.f, 0.f, 0.f, 0.f};

  for (int kt = 0; kt < LKK / 64; ++kt) {
    __syncthreads();  // protect Ks/Vs from previous iteration's readers
    {  // stage K tile [64 x 128]
      int r = t >> 2, c0 = (t & 3) * 32;
      const uint4* src = (const uint4*)(kg + ((size_t)(b * LKK + kt * 64 + r) * PDD + c0));
      uint4* dst = (uint4*)&Ks[r * KST + c0];
      dst[0] = src[0]; dst[1] = src[1]; dst[2] = src[2]; dst[3] = src[3];
    }
    {  // stage vT tile [128 x 64]
      int d = t >> 1, j0l = (t & 1) * 32;
      const uint4* src = (const uint4*)(vtg + ((size_t)(b * PDD + d) * LKK + kt * 64 + j0l));
      uint4* dst = (uint4*)&Vs[d * VST + j0l];
      dst[0] = src[0]; dst[1] = src[1]; dst[2] = src[2]; dst[3] = src[3];
    }
    __syncthreads();

    // S = Q K^T (q pre-scaled by 1/sqrt(128))
    f4v sf[4];
#pragma unroll
    for (int nt = 0; nt < 4; ++nt) {
      f4v s = z4;
#pragma unroll
      for (int kc = 0; kc < 4; ++kc) {
        s8v bk = *(const s8v*)&Ks[(nt * 16 + lc) * KST + kc * 32 + quad * 8];
        s = __builtin_amdgcn_mfma_f32_16x16x32_bf16(aq[kc], bk, s, 0, 0, 0);
      }
      sf[nt] = s;
    }
    // per-row max over 64 keys: reduce 4 frags then 16 lanes in quad
    float mx[4];
#pragma unroll
    for (int g = 0; g < 4; ++g)
      mx[g] = fmaxf(fmaxf(sf[0][g], sf[1][g]), fmaxf(sf[2][g], sf[3][g]));
#pragma unroll
    for (int off = 8; off >= 1; off >>= 1)
#pragma unroll
      for (int g = 0; g < 4; ++g) mx[g] = fmaxf(mx[g], __shfl_xor(mx[g], off, 64));

    float al[4], rs[4], pn[4][4];
#pragma unroll
    for (int g = 0; g < 4; ++g) {
      float mn = fmaxf(m_i[g], mx[g]);
      al[g] = __expf(m_i[g] - mn);
      m_i[g] = mn;
      float s = 0.f;
#pragma unroll
      for (int nt = 0; nt < 4; ++nt) {
        float pv = __expf(sf[nt][g] - mn);
        pn[nt][g] = pv;
        s += pv;
      }
      rs[g] = s;
    }
#pragma unroll
    for (int off = 8; off >= 1; off >>= 1)
#pragma unroll
      for (int g = 0; g < 4; ++g) rs[g] += __shfl_xor(rs[g], off, 64);
#pragma unroll
    for (int g = 0; g < 4; ++g) l_i[g] = l_i[g] * al[g] + rs[g];  // l over ALL keys

    // mask AFTER l update (triu post-softmax, no renorm), write P to per-wave LDS
#pragma unroll
    for (int nt = 0; nt < 4; ++nt) {
      int jg = kt * 64 + nt * 16 + lc;
#pragma unroll
      for (int g = 0; g < 4; ++g) {
        int rg = q0 + wave * 16 + quad * 4 + g;
        float pv = pn[nt][g];
        if (domask && (jg <= rg)) pv = 0.f;
        Ps[wave][(quad * 4 + g) * PST + nt * 16 + lc] = pv;
      }
    }
#pragma unroll
    for (int dt = 0; dt < 8; ++dt)
#pragma unroll
      for (int g = 0; g < 4; ++g) acc[dt][g] *= al[g];

    // P (A-layout via LDS) x V (B-frags from vT)
#pragma unroll
    for (int jc = 0; jc < 2; ++jc) {
      const float* pp = &Ps[wave][lc * PST + jc * 32 + quad * 8];
      float4 p0 = *(const float4*)pp;
      float4 p1 = *(const float4*)(pp + 4);
      s8v ap;
      ap[0] = (short)f2bf(p0.x); ap[1] = (short)f2bf(p0.y);
      ap[2] = (short)f2bf(p0.z); ap[3] = (short)f2bf(p0.w);
      ap[4] = (short)f2bf(p1.x); ap[5] = (short)f2bf(p1.y);
      ap[6] = (short)f2bf(p1.z); ap[7] = (short)f2bf(p1.w);
#pragma unroll
      for (int dt = 0; dt < 8; ++dt) {
        s8v bv = *(const s8v*)&Vs[(dt * 16 + lc) * VST + jc * 32 + quad * 8];
        acc[dt] = __builtin_amdgcn_mfma_f32_16x16x32_bf16(ap, bv, acc[dt], 0, 0, 0);
      }
    }
  }
  // epilogue: out = acc / l (l always > 0: denominator is unmasked softmax sum)
#pragma unroll
  for (int dt = 0; dt < 8; ++dt) {
#pragma unroll
    for (int g = 0; g < 4; ++g) {
      int r = q0 + wave * 16 + quad * 4 + g;
      out[((size_t)(b * LQ + r)) * PDD + dt * 16 + lc] = acc[dt][g] / l_i[g];
    }
  }
}

extern "C" void kernel_launch(void* const* d_in, const int* in_sizes, int n_in,
                              void* d_out, int out_size, void* d_ws, size_t ws_size,
                              hipStream_t stream) {
  const float* x  = (const float*)d_in[0];
  const float* y  = (const float*)d_in[1];
  const float* Wq = (const float*)d_in[2];
  const float* bq = (const float*)d_in[3];
  const float* Wk = (const float*)d_in[4];
  const float* bk = (const float*)d_in[5];
  const float* Wv = (const float*)d_in[6];
  const float* bv = (const float*)d_in[7];
  const int* mask = (const int*)d_in[8];
  char* ws = (char*)d_ws;
  // workspace layout (bf16 buffers), 2 MB each region:
  ushort* qb = (ushort*)(ws);                     // [B*LQ][128]
  ushort* kb = (ushort*)(ws + (size_t)(1 << 21)); // [B*LK][128]
  ushort* vb = (ushort*)(ws + (size_t)(2 << 21)); // [B*LK][128]
  ushort* vt = (ushort*)(ws + (size_t)(3 << 21)); // [B][128][LK]
  ushort* Wt = (ushort*)(ws + (size_t)(4 << 21)); // [3][128][1024]
  float* out = (float*)d_out;

  hipLaunchKernelGGL(k_wtrans, dim3(32, 3), dim3(256), 0, stream, Wq, Wk, Wv, Wt);
  hipLaunchKernelGGL(k_proj, dim3(128, 2), dim3(256), 0, stream, x, y, Wt, bq, bk, bv, qb, kb, vb);
  hipLaunchKernelGGL(k_vtrans, dim3(32, 4), dim3(256), 0, stream, vb, vt);
  hipLaunchKernelGGL(k_attn, dim3(32, 4), dim3(256), 0, stream, qb, kb, vt, mask, out);
}

// Round 2
// 211.043 us; speedup vs baseline: 1.1725x; 1.1725x over previous
//
#include <hip/hip_runtime.h>

typedef short s8v __attribute__((ext_vector_type(8)));
typedef float f4v __attribute__((ext_vector_type(4)));

#define NB 4
#define LQ 2048
#define LKK 2048
#define XS 1024
#define PDD 128

#define PST 68    // P LDS stride (floats): 272B = 16*17 -> 2-way banks (free)
#define AST 132   // acc-partial LDS stride (floats)

__device__ __forceinline__ ushort f2bf(float x) {
  union { float f; uint u; } v; v.f = x;
  uint r = (v.u + 0x7fffu + ((v.u >> 16) & 1u)) >> 16;
  return (ushort)r;
}

// ---------------- W transpose + bf16 cast: Wt[p][n][k] = W_p[k][n] ----------------
__global__ __launch_bounds__(256) void k_wtrans(const float* __restrict__ Wq,
                                                const float* __restrict__ Wk,
                                                const float* __restrict__ Wv,
                                                ushort* __restrict__ Wt) {
  int p = blockIdx.y;
  const float* W = (p == 0) ? Wq : (p == 1) ? Wk : Wv;
  ushort* out = Wt + (size_t)p * (PDD * XS);
  int t = threadIdx.x;
  int n = t >> 1;
  int kk0 = (t & 1) * 16;
  int k0 = blockIdx.x * 32;
  ushort tmp[16];
#pragma unroll
  for (int i = 0; i < 16; ++i) tmp[i] = f2bf(W[(size_t)(k0 + kk0 + i) * PDD + n]);
  uint4 u0, u1;
  u0.x = tmp[0] | ((uint)tmp[1] << 16);  u0.y = tmp[2] | ((uint)tmp[3] << 16);
  u0.z = tmp[4] | ((uint)tmp[5] << 16);  u0.w = tmp[6] | ((uint)tmp[7] << 16);
  u1.x = tmp[8] | ((uint)tmp[9] << 16);  u1.y = tmp[10] | ((uint)tmp[11] << 16);
  u1.z = tmp[12] | ((uint)tmp[13] << 16); u1.w = tmp[14] | ((uint)tmp[15] << 16);
  uint4* dst = (uint4*)&out[n * XS + k0 + kk0];
  dst[0] = u0; dst[1] = u1;
}

// ---------------- projections: p=0: q=(x@Wq+bq)*scale ; p=1: k ; p=2: v -> vT -----
__global__ __launch_bounds__(256) void k_proj(const float* __restrict__ x,
                                              const float* __restrict__ y,
                                              const ushort* __restrict__ Wt,
                                              const float* __restrict__ bq,
                                              const float* __restrict__ bk,
                                              const float* __restrict__ bv,
                                              ushort* __restrict__ qo,
                                              ushort* __restrict__ ko,
                                              ushort* __restrict__ vt) {
  int p = blockIdx.y;
  const float* in = (p == 0) ? x : y;
  const ushort* wt = Wt + (size_t)p * (PDD * XS);
  int row0 = blockIdx.x * 64;
  __shared__ ushort As[64 * 72];   // 144B rows: 16B aligned, 2-way banks (free)
  __shared__ ushort Bs[128 * 72];
  int t = threadIdx.x, wave = t >> 6, lane = t & 63, quad = lane >> 4, lc = lane & 15;
  const f4v z4 = {0.f, 0.f, 0.f, 0.f};
  f4v acc[8];
#pragma unroll
  for (int i = 0; i < 8; ++i) acc[i] = z4;
  for (int k0 = 0; k0 < XS; k0 += 64) {
    {  // stage A [64 rows x 64 k] fp32 -> bf16
      int r = t >> 2, c0 = (t & 3) * 16;
      const float* src = in + (size_t)(row0 + r) * XS + k0 + c0;
      float4 a0 = *(const float4*)src;
      float4 a1 = *(const float4*)(src + 4);
      float4 a2 = *(const float4*)(src + 8);
      float4 a3 = *(const float4*)(src + 12);
      uint4 p0, p1;
      p0.x = f2bf(a0.x) | ((uint)f2bf(a0.y) << 16);
      p0.y = f2bf(a0.z) | ((uint)f2bf(a0.w) << 16);
      p0.z = f2bf(a1.x) | ((uint)f2bf(a1.y) << 16);
      p0.w = f2bf(a1.z) | ((uint)f2bf(a1.w) << 16);
      p1.x = f2bf(a2.x) | ((uint)f2bf(a2.y) << 16);
      p1.y = f2bf(a2.z) | ((uint)f2bf(a2.w) << 16);
      p1.z = f2bf(a3.x) | ((uint)f2bf(a3.y) << 16);
      p1.w = f2bf(a3.z) | ((uint)f2bf(a3.w) << 16);
      *(uint4*)&As[r * 72 + c0] = p0;
      *(uint4*)&As[r * 72 + c0 + 8] = p1;
    }
    {  // stage B [128 n x 64 k] bf16 (row-contiguous in Wt)
      int n = t >> 1, kk0 = (t & 1) * 32;
      const ushort* s0 = wt + (size_t)n * XS + k0 + kk0;
      uint4 u0 = *(const uint4*)s0;
      uint4 u1 = *(const uint4*)(s0 + 8);
      uint4 u2 = *(const uint4*)(s0 + 16);
      uint4 u3 = *(const uint4*)(s0 + 24);
      *(uint4*)&Bs[n * 72 + kk0] = u0;
      *(uint4*)&Bs[n * 72 + kk0 + 8] = u1;
      *(uint4*)&Bs[n * 72 + kk0 + 16] = u2;
      *(uint4*)&Bs[n * 72 + kk0 + 24] = u3;
    }
    __syncthreads();
#pragma unroll
    for (int kc = 0; kc < 2; ++kc) {
      s8v a = *(const s8v*)&As[(wave * 16 + lc) * 72 + kc * 32 + quad * 8];
#pragma unroll
      for (int nt = 0; nt < 8; ++nt) {
        s8v bfr = *(const s8v*)&Bs[(nt * 16 + lc) * 72 + kc * 32 + quad * 8];
        acc[nt] = __builtin_amdgcn_mfma_f32_16x16x32_bf16(a, bfr, acc[nt], 0, 0, 0);
      }
    }
    __syncthreads();
  }
  const float qscale = 0.08838834764831845f;  // 1/sqrt(128) folded into q
  const float* bias = (p == 0) ? bq : (p == 1) ? bk : bv;
  if (p < 2) {
    ushort* o = (p == 0) ? qo : ko;
    float scl = (p == 0) ? qscale : 1.0f;
#pragma unroll
    for (int nt = 0; nt < 8; ++nt) {
      int col = nt * 16 + lc;
      float bb = bias[col];
#pragma unroll
      for (int g = 0; g < 4; ++g) {
        int r = row0 + wave * 16 + quad * 4 + g;  // C-layout: row = quad*4+reg
        o[(size_t)r * PDD + col] = f2bf((acc[nt][g] + bb) * scl);
      }
    }
  } else {  // v: write transposed vT[b][col][rr], 4 consecutive rows -> 8B store
    int rbase = row0 + wave * 16 + quad * 4;
    int b = rbase >> 11, rr = rbase & 2047;
#pragma unroll
    for (int nt = 0; nt < 8; ++nt) {
      int col = nt * 16 + lc;
      float bb = bias[col];
      ushort4 pk;
      pk.x = f2bf(acc[nt][0] + bb);
      pk.y = f2bf(acc[nt][1] + bb);
      pk.z = f2bf(acc[nt][2] + bb);
      pk.w = f2bf(acc[nt][3] + bb);
      *(ushort4*)&vt[((size_t)(b * PDD + col)) * LKK + rr] = pk;
    }
  }
}

// ------- fused attention: per-wave flash, in-block KV-split-4, LDS merge ---------
__global__ __launch_bounds__(256, 4) void k_attn(const ushort* __restrict__ qg,
                                                 const ushort* __restrict__ kg,
                                                 const ushort* __restrict__ vtg,
                                                 const int* __restrict__ maskp,
                                                 float* __restrict__ out) {
  __shared__ float Ps[4][16 * PST];    // per-wave P transpose buffer
  __shared__ float accS[4][16 * AST];  // per-wave output partials
  __shared__ float mS[4][16], lS[4][16];
  int b = blockIdx.y;
  int q0 = blockIdx.x * 16;
  int t = threadIdx.x;
  int wave = t >> 6, lane = t & 63, quad = lane >> 4, lc = lane & 15;
  int domask = *maskp;

  // Q A-frags direct from global: A[m=lc][k=quad*8+j]
  const ushort* qrow = qg + ((size_t)(b * LQ + q0 + lc)) * PDD + quad * 8;
  s8v aq[4];
#pragma unroll
  for (int kc = 0; kc < 4; ++kc) aq[kc] = *(const s8v*)(qrow + kc * 32);

  const f4v z4 = {0.f, 0.f, 0.f, 0.f};
  f4v acc[8];
#pragma unroll
  for (int i = 0; i < 8; ++i) acc[i] = z4;
  float m_i[4] = {-1e30f, -1e30f, -1e30f, -1e30f};
  float l_i[4] = {0.f, 0.f, 0.f, 0.f};

  // wave w handles key-tiles kt = w, w+4, ..., w+28 (8 tiles of 64 keys)
  const ushort* kbase = kg + ((size_t)(b * LKK + wave * 64 + lc)) * PDD + quad * 8;
  const ushort* vbase = vtg + ((size_t)(b * PDD + lc)) * LKK + wave * 64 + quad * 8;

  for (int i = 0; i < 8; ++i) {
    int kt = wave + i * 4;
    const ushort* kp = kbase + (size_t)(i * 256) * PDD;
    // S = Q K^T (q pre-scaled)
    f4v sf[4];
#pragma unroll
    for (int nt = 0; nt < 4; ++nt) {
      f4v s = z4;
#pragma unroll
      for (int kc = 0; kc < 4; ++kc) {
        s8v bk = *(const s8v*)(kp + (size_t)(nt * 16) * PDD + kc * 32);
        s = __builtin_amdgcn_mfma_f32_16x16x32_bf16(aq[kc], bk, s, 0, 0, 0);
      }
      sf[nt] = s;
    }
    // per-row max over this 64-key tile (rows live across 16 lc lanes of quad)
    float mx[4];
#pragma unroll
    for (int g = 0; g < 4; ++g)
      mx[g] = fmaxf(fmaxf(sf[0][g], sf[1][g]), fmaxf(sf[2][g], sf[3][g]));
#pragma unroll
    for (int off = 8; off >= 1; off >>= 1)
#pragma unroll
      for (int g = 0; g < 4; ++g) mx[g] = fmaxf(mx[g], __shfl_xor(mx[g], off, 64));

    float al[4], rs[4];
#pragma unroll
    for (int g = 0; g < 4; ++g) {
      float mn = fmaxf(m_i[g], mx[g]);
      al[g] = __expf(m_i[g] - mn);
      m_i[g] = mn;
      rs[g] = 0.f;
      int rg = q0 + quad * 4 + g;
#pragma unroll
      for (int nt = 0; nt < 4; ++nt) {
        float pv = __expf(sf[nt][g] - mn);
        rs[g] += pv;  // l over ALL keys (mask is post-softmax, no renorm)
        int jg = kt * 64 + nt * 16 + lc;
        if (domask && (jg <= rg)) pv = 0.f;
        Ps[wave][(quad * 4 + g) * PST + nt * 16 + lc] = pv;
      }
    }
#pragma unroll
    for (int off = 8; off >= 1; off >>= 1)
#pragma unroll
      for (int g = 0; g < 4; ++g) rs[g] += __shfl_xor(rs[g], off, 64);
#pragma unroll
    for (int g = 0; g < 4; ++g) l_i[g] = l_i[g] * al[g] + rs[g];
#pragma unroll
    for (int dt = 0; dt < 8; ++dt)
#pragma unroll
      for (int g = 0; g < 4; ++g) acc[dt][g] *= al[g];

    // P (A-layout via per-wave LDS) x V (B-frags direct from vT global)
#pragma unroll
    for (int jc = 0; jc < 2; ++jc) {
      const float* pp = &Ps[wave][lc * PST + jc * 32 + quad * 8];
      float4 p0 = *(const float4*)pp;
      float4 p1 = *(const float4*)(pp + 4);
      s8v ap;
      ap[0] = (short)f2bf(p0.x); ap[1] = (short)f2bf(p0.y);
      ap[2] = (short)f2bf(p0.z); ap[3] = (short)f2bf(p0.w);
      ap[4] = (short)f2bf(p1.x); ap[5] = (short)f2bf(p1.y);
      ap[6] = (short)f2bf(p1.z); ap[7] = (short)f2bf(p1.w);
#pragma unroll
      for (int dt = 0; dt < 8; ++dt) {
        s8v bv4 = *(const s8v*)(vbase + (size_t)(dt * 16) * LKK + i * 256 + jc * 32);
        acc[dt] = __builtin_amdgcn_mfma_f32_16x16x32_bf16(ap, bv4, acc[dt], 0, 0, 0);
      }
    }
  }

  // write per-wave partials
#pragma unroll
  for (int dt = 0; dt < 8; ++dt)
#pragma unroll
    for (int g = 0; g < 4; ++g)
      accS[wave][(quad * 4 + g) * AST + dt * 16 + lc] = acc[dt][g];
  if (lc == 0) {
#pragma unroll
    for (int g = 0; g < 4; ++g) {
      mS[wave][quad * 4 + g] = m_i[g];
      lS[wave][quad * 4 + g] = l_i[g];
    }
  }
  __syncthreads();

  // merge 4 partials: row = t>>4, 8 dims per thread
  {
    int row = t >> 4, c0 = (t & 15) * 8;
    float m0 = mS[0][row], m1 = mS[1][row], m2 = mS[2][row], m3 = mS[3][row];
    float M = fmaxf(fmaxf(m0, m1), fmaxf(m2, m3));
    float w0 = __expf(m0 - M), w1 = __expf(m1 - M), w2 = __expf(m2 - M), w3 = __expf(m3 - M);
    float L = lS[0][row] * w0 + lS[1][row] * w1 + lS[2][row] * w2 + lS[3][row] * w3;
    float inv = 1.0f / L;
    float4 o0, o1;
    const float* a0 = &accS[0][row * AST + c0];
    const float* a1 = &accS[1][row * AST + c0];
    const float* a2 = &accS[2][row * AST + c0];
    const float* a3 = &accS[3][row * AST + c0];
    float4 x0 = *(const float4*)a0, y0 = *(const float4*)(a0 + 4);
    float4 x1 = *(const float4*)a1, y1 = *(const float4*)(a1 + 4);
    float4 x2 = *(const float4*)a2, y2 = *(const float4*)(a2 + 4);
    float4 x3 = *(const float4*)a3, y3 = *(const float4*)(a3 + 4);
    o0.x = (x0.x * w0 + x1.x * w1 + x2.x * w2 + x3.x * w3) * inv;
    o0.y = (x0.y * w0 + x1.y * w1 + x2.y * w2 + x3.y * w3) * inv;
    o0.z = (x0.z * w0 + x1.z * w1 + x2.z * w2 + x3.z * w3) * inv;
    o0.w = (x0.w * w0 + x1.w * w1 + x2.w * w2 + x3.w * w3) * inv;
    o1.x = (y0.x * w0 + y1.x * w1 + y2.x * w2 + y3.x * w3) * inv;
    o1.y = (y0.y * w0 + y1.y * w1 + y2.y * w2 + y3.y * w3) * inv;
    o1.z = (y0.z * w0 + y1.z * w1 + y2.z * w2 + y3.z * w3) * inv;
    o1.w = (y0.w * w0 + y1.w * w1 + y2.w * w2 + y3.w * w3) * inv;
    float* op = out + ((size_t)(b * LQ + q0 + row)) * PDD + c0;
    *(float4*)op = o0;
    *(float4*)(op + 4) = o1;
  }
}

extern "C" void kernel_launch(void* const* d_in, const int* in_sizes, int n_in,
                              void* d_out, int out_size, void* d_ws, size_t ws_size,
                              hipStream_t stream) {
  const float* x  = (const float*)d_in[0];
  const float* y  = (const float*)d_in[1];
  const float* Wq = (const float*)d_in[2];
  const float* bq = (const float*)d_in[3];
  const float* Wk = (const float*)d_in[4];
  const float* bk = (const float*)d_in[5];
  const float* Wv = (const float*)d_in[6];
  const float* bv = (const float*)d_in[7];
  const int* mask = (const int*)d_in[8];
  char* ws = (char*)d_ws;
  ushort* qb = (ushort*)(ws);                     // [B*LQ][128] bf16
  ushort* kb = (ushort*)(ws + (size_t)(1 << 21)); // [B*LK][128] bf16
  ushort* vt = (ushort*)(ws + (size_t)(2 << 21)); // [B][128][LK] bf16
  ushort* Wt = (ushort*)(ws + (size_t)(3 << 21)); // [3][128][1024] bf16
  float* out = (float*)d_out;

  hipLaunchKernelGGL(k_wtrans, dim3(32, 3), dim3(256), 0, stream, Wq, Wk, Wv, Wt);
  hipLaunchKernelGGL(k_proj, dim3(128, 3), dim3(256), 0, stream, x, y, Wt, bq, bk, bv, qb, kb, vt);
  hipLaunchKernelGGL(k_attn, dim3(128, 4), dim3(256), 0, stream, qb, kb, vt, mask, out);
}